// Round 11
// baseline (470.845 us; speedup 1.0000x reference)
//
#include <hip/hip_runtime.h>
#include <hip/hip_bf16.h>

typedef int i32x4 __attribute__((ext_vector_type(4)));
typedef unsigned int u32;
typedef unsigned long long u64;
typedef long long ll;

// async 16B global->LDS copy. LDS dest = wave-uniform base + lane*16.
__device__ __forceinline__ void load_lds16(const void* g, void* l) {
  __builtin_amdgcn_global_load_lds(
      (const __attribute__((address_space(1))) u32*)g,
      (__attribute__((address_space(3))) u32*)l, 16, 0, 0);
}

// s_waitcnt immediates: vmcnt in [3:0]|[15:14], all other counters = don't wait.
#define WAITCNT_VM8 0x3FF8   // vmcnt(8)
#define WAITCNT_VM0 0x3FF0   // vmcnt(0)

// ---------------------------------------------------------------------------
// prep_all: weight packing via LDS transpose (coalesced reads) + totw sums.
// Grid: [0,88) transpose blocks (each owns 8 oc of one mf-half);
//       blk==88: w0q custom pack + zbuf + w0 sums.
//   wNp : i8 [s=tap*3+ch][mf(MF)][q4][col16][e16]; ci = ch*64+q*16+e
//   w0q : i8 [ch2][mf12][q4][colA16][e16], CUSTOM k-order:
//         ch0: ky=q, ci=e/5, kx=e%5 (e<15); ch1: q==0 -> ky=4; all else 0.
//   zbuf : 0x80 fill (B-pad reads give value-128 uniformly)
// ---------------------------------------------------------------------------
__global__ __launch_bounds__(256) void prep_all(
    const float* __restrict__ w0, const float* __restrict__ w1,
    const float* __restrict__ w2, const float* __restrict__ w3,
    signed char* __restrict__ w0q, signed char* __restrict__ w1p,
    signed char* __restrict__ w2p, signed char* __restrict__ w3p,
    signed char* __restrict__ zbuf,
    int* __restrict__ totw0, int* __restrict__ totw1,
    int* __restrict__ totw2, int* __restrict__ totw3)
{
  __shared__ signed char ldsw[8 * 4800];   // 38400 B
  const int blk = blockIdx.x;
  const int tid = threadIdx.x;

  if (blk < 88) {
    const float* wsrc; signed char* wdst; int* tot; int MF, sub;
    if (blk < 24)      { wsrc = w1; wdst = w1p; tot = totw1; MF = 12; sub = blk; }
    else if (blk < 48) { wsrc = w2; wdst = w2p; tot = totw2; MF = 12; sub = blk - 24; }
    else               { wsrc = w3; wdst = w3p; tot = totw3; MF = 20; sub = blk - 48; }
    const int mf = sub >> 1, half = sub & 1, colbase = half * 8;
    const int ocb = mf * 16 + colbase;
    for (int o = 0; o < 8; o++) {
      const float* src = wsrc + (size_t)(ocb + o) * 4800;
      int s = 0;
      for (int j = tid; j < 4800; j += 256) {
        int v = (int)rintf(src[j]);
        ldsw[o * 4800 + j] = (signed char)v;
        s += v;
      }
      atomicAdd(&tot[ocb + o], s);
    }
    __syncthreads();
    for (int u = tid; u < 9600; u += 256) {
      int eu = u & 3, colL = (u >> 2) & 7, q = (u >> 5) & 3, t = u >> 7;
      int tap = t / 3, ch = t - 3 * tap;
      int ci0 = ch * 64 + q * 16 + eu * 4;
      const signed char* sp = ldsw + colL * 4800 + tap;
      u32 wv = 0;
      #pragma unroll
      for (int bb = 0; bb < 4; bb++)
        wv |= ((u32)(unsigned char)sp[(ci0 + bb) * 25]) << (8 * bb);
      *(u32*)(wdst + ((size_t)t * MF + mf) * 1024 +
              (q * 16 + colbase + colL) * 16 + eu * 4) = wv;
    }
  } else {
    if (tid < 128) ((u64*)zbuf)[tid] = 0x8080808080808080ULL;
    for (int i = tid; i < 24576; i += 256) {
      int e = i & 15, colA = (i >> 4) & 15, q = (i >> 8) & 3, t = i >> 10;
      int mf = t % 12, ch = t / 12;
      signed char v = 0;
      if (e < 15 && (ch == 0 || q == 0)) {
        int ky = (ch == 0) ? q : 4;
        int ci = e / 5, kx = e - ci * 5;
        v = (signed char)(int)rintf(
            w0[((mf * 16 + colA) * 3 + ci) * 25 + ky * 5 + kx]);
      }
      w0q[i] = v;
    }
    for (int oc = tid; oc < 192; oc += 256) {
      const float* p = w0 + (size_t)oc * 75;
      int s = 0;
      #pragma unroll 5
      for (int j = 0; j < 75; j++) s += (int)rintf(p[j]);
      totw0[oc] = s;
    }
  }
}

// ---------------------------------------------------------------------------
// conv0F: fused layer-0 (unchanged from R10). Block = 64-px strip, 3 waves.
// ---------------------------------------------------------------------------
__global__ __launch_bounds__(192, 3) void conv0F(
    const float* __restrict__ x, const signed char* __restrict__ wq,
    const float* __restrict__ bias, const float* __restrict__ mulv,
    const int* __restrict__ totw,
    const int* __restrict__ reluP, const int* __restrict__ mdP,
    unsigned char* __restrict__ outA)
{
  __shared__ signed char ilds[3][5][132];

  const int tid = threadIdx.x;
  const int lane = tid & 63;
  const int col = lane & 15;
  const int quad = lane >> 4;
  const int w = tid >> 6;
  const int blk = blockIdx.x;
  const int oxblk = blk & 3;
  const int oy = (blk >> 2) & 255;
  const int b = blk >> 10;
  const int oxbase = oxblk * 64;

  i32x4 afr[2][4];
  #pragma unroll
  for (int ch = 0; ch < 2; ch++)
    #pragma unroll
    for (int i = 0; i < 4; i++)
      afr[ch][i] = *(const i32x4*)(wq + ch * 12288 + (w * 4 + i) * 1024 + lane * 16);

  const float* xb = x + (size_t)b * 3 * 512 * 512;
  for (int i = tid; i < 990; i += 192) {
    int j = i % 66; int t = i / 66; int r = t % 5; int ci = t / 5;
    int iy = 2 * oy - 2 + r;
    int ix = 2 * oxbase - 2 + 2 * j;
    int v0 = -128, v1 = -128;
    if ((unsigned)iy < 512u) {
      const float* row = xb + ((size_t)ci * 512 + iy) * 512;
      if ((unsigned)ix < 512u) {
        float xv = rintf(row[ix] * 256.0f);
        v0 = (int)fminf(fmaxf(xv, 0.0f), 255.0f) - 128;
      }
      if ((unsigned)(ix + 1) < 512u) {
        float xv = rintf(row[ix + 1] * 256.0f);
        v1 = (int)fminf(fmaxf(xv, 0.0f), 255.0f) - 128;
      }
    }
    *(unsigned short*)&ilds[ci][r][2 * j] =
        (unsigned short)((v0 & 0xFF) | ((v1 & 0xFF) << 8));
  }
  __syncthreads();

  i32x4 acc[4][4];
  #pragma unroll
  for (int fm = 0; fm < 4; fm++)
    #pragma unroll
    for (int fn = 0; fn < 4; fn++) acc[fm][fn] = (i32x4){0, 0, 0, 0};

  #pragma unroll
  for (int ch = 0; ch < 2; ch++) {
    const int row = (ch == 0) ? quad : 4;
    i32x4 bfr[4];
    #pragma unroll
    for (int fn = 0; fn < 4; fn++) {
      const int xb2 = 2 * (fn * 16 + col);
      const int o8 = (xb2 & 3) * 8;
      const int ab = xb2 & ~3;
      u64 w0_, w1_, w2_;
      {
        const u32* p0 = (const u32*)&ilds[0][row][ab];
        const u32* p1 = (const u32*)&ilds[1][row][ab];
        const u32* p2 = (const u32*)&ilds[2][row][ab];
        w0_ = (u64)p0[0] | ((u64)p0[1] << 32);
        w1_ = (u64)p1[0] | ((u64)p1[1] << 32);
        w2_ = (u64)p2[0] | ((u64)p2[1] << 32);
      }
      u32 a0 = (u32)(w0_ >> o8);
      u32 a1 = ((u32)(w0_ >> (o8 + 32)) & 0xFFu) | (((u32)(w1_ >> o8)) << 8);
      u32 a2 = ((u32)(w1_ >> (o8 + 24)) & 0xFFFFu) | (((u32)(w2_ >> o8)) << 16);
      u32 a3 = (u32)(w2_ >> (o8 + 16));
      bfr[fn] = (i32x4){(int)a0, (int)a1, (int)a2, (int)a3};
    }
    #pragma unroll
    for (int fm = 0; fm < 4; fm++)
      #pragma unroll
      for (int fn = 0; fn < 4; fn++)
        acc[fm][fn] = __builtin_amdgcn_mfma_i32_16x16x64_i8(
            afr[ch][fm], bfr[fn], acc[fm][fn], 0, 0, 0);
  }

  const size_t pix0 = ((size_t)(b * 256 + oy)) * 256 + oxbase;
  const int rl = reluP[0];
  const int sh = mdP[0];
  const ll clpv_ll = llrint(255.0 / (double)rl * 16777216.0);
  const int clpv = clpv_ll > 0x7FFFFFFFLL ? 0x7FFFFFFF : (int)clpv_ll;
  const int sclv = (int)((rl + 4) >> 3);
  const int rnd = 1 << (sh - 1);
  #pragma unroll
  for (int fm = 0; fm < 4; fm++) {
    const int oc0 = w * 64 + fm * 16 + quad * 4;
    int bim[4], mu32[4];
    #pragma unroll
    for (int r = 0; r < 4; r++) {
      int bi = (int)llrintf(bias[oc0 + r] * 256.0f) + 128 * totw[oc0 + r];
      mu32[r] = (int)llrintf(mulv[oc0 + r]);
      bim[r] = bi * mu32[r];
    }
    #pragma unroll
    for (int fn = 0; fn < 4; fn++) {
      const size_t pix = pix0 + fn * 16 + col;
      u32 wd = 0;
      #pragma unroll
      for (int r = 0; r < 4; r++) {
        int vi = acc[fm][fn][r] * mu32[r] + bim[r];
        int y = (vi + rnd) >> sh;
        y = y < 0 ? 0 : (y > clpv ? clpv : y);
        y = (y * sclv + (1 << 20)) >> 21;
        wd |= (((u32)y ^ 0x80u) & 0xFFu) << (8 * r);
      }
      *(u32*)(outA + pix * 192 + oc0) = wd;
    }
  }
}

// ---------------------------------------------------------------------------
// Layers 1-3: BARRIER-FREE implicit GEMM, mfma_i32_16x16x64_i8.
// One wave per block (64 thr). The wave stages its own 4 B frags per step
// into a private 2x4KB LDS dbuf via global_load_lds and synchronizes with
// explicit s_waitcnt vmcnt(8) only (8 = this step's 4 B-stage + 4 A loads;
// FIFO drains the previous step's group). No __syncthreads anywhere.
// A-frags register-rotated (aA/aB). Always-stage keeps the count uniform
// (past-end taps are mask-deflected to zbuf; A over-reads land in ws).
// ---------------------------------------------------------------------------
template <int COUT, int HIN, int WIN, int HOUT, int WOUT, int KSPLIT, bool DIRECT>
__global__ __launch_bounds__(64, 4) void convS(
    const signed char* __restrict__ act, const signed char* __restrict__ wp,
    const float* __restrict__ bias, const float* __restrict__ mulv,
    const int* __restrict__ totw,
    const int* __restrict__ reluP, const int* __restrict__ mdP,
    const signed char* __restrict__ zbuf,
    unsigned char* __restrict__ outA, int* __restrict__ outP)
{
  constexpr int CIN = 192;
  constexpr int MF = COUT / 16;
  constexpr int SAe = MF * 1024;         // A bytes per step
  constexpr int OCT = COUT / 64;
  constexpr int TX = WOUT / 16;
  constexpr int TYB = HOUT / 4;
  constexpr int TPP = 25 / KSPLIT;
  constexpr int NSTEP = TPP * 3;
  constexpr int PSZ = 4 * HOUT * WOUT * COUT;
  constexpr int ROWST = 2 * WIN * CIN;   // byte stride between fn rows

  __shared__ __align__(16) char smem[2 * 4096];

  const int lane = threadIdx.x;
  const int col = lane & 15;
  const int quad = lane >> 4;
  const int part = blockIdx.y;

  int bx = blockIdx.x;
  const int oct = bx % OCT; bx /= OCT;
  const int tx = bx % TX; bx /= TX;
  const int ty = bx % TYB;
  const int b = bx / TYB;
  const int ox0 = tx * 16;
  const int oy0 = ty * 4;

  // B base (fn row 0) + packed pad masks
  const int oxv = ox0 + col;
  const signed char* bbase =
      act + ((size_t)b * HIN * WIN + (size_t)(2 * oy0) * WIN + 2 * oxv) * CIN
      + quad * 16;
  int bmx = 0;
  #pragma unroll
  for (int kk = 0; kk < 5; kk++)
    if ((unsigned)(2 * oxv + kk - 2) < (unsigned)WIN) bmx |= 1 << kk;
  u32 bmyP = 0;
  #pragma unroll
  for (int p = 0; p < 4; p++) {
    int oyv = oy0 + p;
    u32 my = 0;
    #pragma unroll
    for (int kk = 0; kk < 5; kk++)
      if ((unsigned)(2 * oyv + kk - 2) < (unsigned)HIN) my |= 1 << kk;
    bmyP |= my << (8 * p);
  }
  const signed char* zp = zbuf + quad * 16;

  int kxS, kyS, chS;
  auto stage = [&](int sel) {
    const int offB = ((kyS - 2) * WIN + (kxS - 2)) * CIN + chS * 64;
    #pragma unroll
    for (int p = 0; p < 4; p++) {
      bool v = ((bmx >> kxS) & 1) && ((bmyP >> (8 * p + kyS)) & 1);
      const signed char* g = v ? (bbase + p * ROWST + offB) : zp;
      load_lds16(g, smem + sel * 4096 + p * 1024);
    }
  };
  auto adv = [&]() {
    chS++;
    if (chS == 3) { chS = 0; kxS++; if (kxS == 5) { kxS = 0; kyS++; } }
  };

  i32x4 acc[4][4];
  #pragma unroll
  for (int fm = 0; fm < 4; fm++)
    #pragma unroll
    for (int fn = 0; fn < 4; fn++) acc[fm][fn] = (i32x4){0, 0, 0, 0};

  // preload: B(0) -> buf0 ; A(0) -> aA
  const int tap0 = part * TPP;
  kyS = tap0 / 5; kxS = tap0 - 5 * kyS; chS = 0;
  stage(0); adv();
  const signed char* aptr = wp + (size_t)(tap0 * 3) * SAe + oct * 4096 + lane * 16;
  i32x4 aA[4], aB[4];
  #pragma unroll
  for (int i = 0; i < 4; i++) aA[i] = *(const i32x4*)(aptr + i * 1024);
  aptr += SAe;

  auto comp = [&](int base, i32x4 (&a)[4]) {
    const char* pB = smem + base + lane * 16;
    i32x4 bfr[4];
    #pragma unroll
    for (int i = 0; i < 4; i++)
      bfr[i] = *(const i32x4*)(pB + i * 1024);
    #pragma unroll
    for (int fm = 0; fm < 4; fm++)
      #pragma unroll
      for (int fn = 0; fn < 4; fn++)
        acc[fm][fn] = __builtin_amdgcn_mfma_i32_16x16x64_i8(
            a[fm], bfr[fn], acc[fm][fn], 0, 0, 0);
  };

  #pragma unroll 1
  for (int sl = 0; sl < NSTEP; sl += 2) {
    // step sl: compute buf0/aA ; stage B(sl+1)->buf1, A(sl+1)->aB
    stage(1); adv();
    #pragma unroll
    for (int i = 0; i < 4; i++) aB[i] = *(const i32x4*)(aptr + i * 1024);
    aptr += SAe;
    __builtin_amdgcn_sched_barrier(0);
    __builtin_amdgcn_s_waitcnt(WAITCNT_VM8);   // B(sl), A(sl) complete
    __builtin_amdgcn_sched_barrier(0);
    comp(0, aA);

    if (sl + 1 < NSTEP) {
      stage(0); adv();
      #pragma unroll
      for (int i = 0; i < 4; i++) aA[i] = *(const i32x4*)(aptr + i * 1024);
      aptr += SAe;
      __builtin_amdgcn_sched_barrier(0);
      __builtin_amdgcn_s_waitcnt(WAITCNT_VM8); // B(sl+1), A(sl+1) complete
      __builtin_amdgcn_sched_barrier(0);
      comp(4096, aB);
    }
  }
  __builtin_amdgcn_s_waitcnt(WAITCNT_VM0);     // drain trailing over-stages

  // ---- epilogue ----
  if constexpr (DIRECT) {
    const int rl = reluP[0];
    const int sh = mdP[0] - 8;
    const ll clpv = llrint(255.0 / (double)rl * 16777216.0);
    const ll sclv = (ll)((rl + 4) >> 3);
    #pragma unroll
    for (int fm = 0; fm < 4; fm++) {
      const int oc0 = oct * 64 + fm * 16 + quad * 4;
      ll bi[4], mu[4];
      #pragma unroll
      for (int r = 0; r < 4; r++) {
        bi[r] = llrintf(bias[oc0 + r]) + 128LL * totw[oc0 + r];
        mu[r] = llrintf(mulv[oc0 + r]);
      }
      #pragma unroll
      for (int fn = 0; fn < 4; fn++) {
        const int oyv = oy0 + fn;
        u32 wd = 0;
        #pragma unroll
        for (int r = 0; r < 4; r++) {
          ll vi = ((ll)acc[fm][fn][r] + bi[r]) * mu[r];
          ll y = (vi + (1LL << (sh - 1))) >> sh;
          y = y < 0 ? 0LL : (y > clpv ? clpv : y);
          y = (y * sclv + (1LL << 20)) >> 21;
          wd |= (((u32)y ^ 0x80u) & 0xFFu) << (8 * r);
        }
        *(u32*)(outA + ((size_t)((b * HOUT + oyv) * WOUT + oxv)) * COUT + oc0) = wd;
      }
    }
  } else {
    int* pout = outP + (size_t)part * PSZ;
    #pragma unroll
    for (int fm = 0; fm < 4; fm++) {
      const int oc0 = oct * 64 + fm * 16 + quad * 4;
      #pragma unroll
      for (int fn = 0; fn < 4; fn++) {
        const int oyv = oy0 + fn;
        *(i32x4*)(pout + ((size_t)((b * HOUT + oyv) * WOUT + oxv)) * COUT + oc0) =
            acc[fm][fn];
      }
    }
  }
}

// ---------------------------------------------------------------------------
// reduce2: sum 5 L2 partials + integer epilogue -> act3 (i8, channels-last).
// ---------------------------------------------------------------------------
__global__ __launch_bounds__(256) void reduce2(
    const int* __restrict__ partP, const float* __restrict__ bias,
    const float* __restrict__ mulv, const int* __restrict__ totw,
    const int* __restrict__ reluP, const int* __restrict__ mdP,
    unsigned char* __restrict__ outA)
{
  const int gid = blockIdx.x * 256 + threadIdx.x;   // 786432
  const int PSZ4 = 4 * 64 * 64 * 192 / 4;
  const int4* pp = (const int4*)partP;
  int4 sv = pp[gid];
  #pragma unroll
  for (int p = 1; p < 5; p++) {
    int4 v = pp[(size_t)p * PSZ4 + gid];
    sv.x += v.x; sv.y += v.y; sv.z += v.z; sv.w += v.w;
  }
  int sa[4] = {sv.x, sv.y, sv.z, sv.w};
  const int oc0 = (gid * 4) % 192;
  const int rl = reluP[0];
  const int sh = mdP[0] - 8;
  const ll clpv = llrint(255.0 / (double)rl * 16777216.0);
  const ll sclv = (ll)((rl + 4) >> 3);
  u32 wd = 0;
  #pragma unroll
  for (int r = 0; r < 4; r++) {
    ll bi = llrintf(bias[oc0 + r]) + 128LL * totw[oc0 + r];
    ll mu = llrintf(mulv[oc0 + r]);
    ll vi = ((ll)sa[r] + bi) * mu;
    ll y = (vi + (1LL << (sh - 1))) >> sh;
    y = y < 0 ? 0LL : (y > clpv ? clpv : y);
    y = (y * sclv + (1LL << 20)) >> 21;
    wd |= (((u32)y ^ 0x80u) & 0xFFu) << (8 * r);
  }
  ((u32*)outA)[gid] = wd;
}

// ---------------------------------------------------------------------------
// reduce3: sum 5 L3 partials + final shift -> d_out f32 NCHW (coalesced write).
// ---------------------------------------------------------------------------
__global__ __launch_bounds__(256) void reduce3(
    const int* __restrict__ partP, const float* __restrict__ b3,
    const float* __restrict__ mul3, const int* __restrict__ totw3,
    const int* __restrict__ mdP, const int* __restrict__ gaP,
    float* __restrict__ outF)
{
  const int gid = blockIdx.x * 256 + threadIdx.x;   // 1310720
  int t = gid;
  const int ox = t & 31; t >>= 5;
  const int oy = t & 31; t >>= 5;
  const int oc = t % 320;
  const int b  = t / 320;
  const int PSZ = 4 * 32 * 32 * 320;
  const size_t src = ((size_t)((b * 32 + oy) * 32 + ox)) * 320 + oc;
  ll s = 0;
  #pragma unroll
  for (int p = 0; p < 5; p++) s += partP[(size_t)p * PSZ + src];
  const int sh = mdP[0] - gaP[0];
  const ll bi = llrintf(b3[oc]) + 128LL * totw3[oc];
  const ll mu = llrintf(mul3[oc]);
  const ll y = ((s + bi) * mu + (1LL << (sh - 1))) >> sh;
  outF[gid] = (float)y;
}

// ---------------------------------------------------------------------------
extern "C" void kernel_launch(void* const* d_in, const int* in_sizes, int n_in,
                              void* d_out, int out_size, void* d_ws, size_t ws_size,
                              hipStream_t stream)
{
  const float* x    = (const float*)d_in[0];
  const float* w0   = (const float*)d_in[1];
  const float* b0   = (const float*)d_in[2];
  const float* w1   = (const float*)d_in[3];
  const float* b1   = (const float*)d_in[4];
  const float* w2   = (const float*)d_in[5];
  const float* b2   = (const float*)d_in[6];
  const float* w3   = (const float*)d_in[7];
  const float* b3   = (const float*)d_in[8];
  const float* mul0 = (const float*)d_in[9];
  const float* mul1 = (const float*)d_in[10];
  const float* mul2 = (const float*)d_in[11];
  const float* mul3 = (const float*)d_in[12];
  const int* relu0  = (const int*)d_in[13];
  const int* relu1  = (const int*)d_in[14];
  const int* relu2  = (const int*)d_in[15];
  const int* md0    = (const int*)d_in[16];
  const int* md1    = (const int*)d_in[17];
  const int* md2    = (const int*)d_in[18];
  const int* md3    = (const int*)d_in[19];
  const int* ga     = (const int*)d_in[20];

  char* ws = (char*)d_ws;
  size_t off = 0;
  signed char* zbuf = (signed char*)(ws + off); off += 1024;
  signed char* w0q  = (signed char*)(ws + off); off += 24576;
  signed char* w1p  = (signed char*)(ws + off); off += 921600;
  signed char* w2p  = (signed char*)(ws + off); off += 921600;
  signed char* w3p  = (signed char*)(ws + off); off += 1536000;
  int*         totw1= (int*)        (ws + off); off += 192 * 4;
  int*         totw2= (int*)        (ws + off); off += 192 * 4;
  int*         totw3= (int*)        (ws + off); off += 320 * 4;
  int*         totw0= (int*)        (ws + off); off += 192 * 4;
  unsigned char* act1 = (unsigned char*)(ws + off); off += (size_t)4 * 256 * 256 * 192;
  unsigned char* act2 = (unsigned char*)(ws + off); off += (size_t)4 * 128 * 128 * 192;
  unsigned char* act3 = (unsigned char*)(ws + off); off += (size_t)4 * 64 * 64 * 192;
  int*         partl  = (int*)(ws + off); off += (size_t)5 * 4 * 64 * 64 * 192 * 4; // 62.9MB
  (void)ws_size; (void)in_sizes; (void)n_in; (void)out_size;

  hipMemsetAsync(totw1, 0, (192 + 192 + 320 + 192) * 4, stream);
  // weight packing (LDS transpose) + weight sums
  prep_all<<<89, 256, 0, stream>>>(w0, w1, w2, w3, w0q, w1p, w2p, w3p,
                                   zbuf, totw0, totw1, totw2, totw3);
  // L0 fused: quantize + in-register im2col + GEMM (M=192, N=262144, K=128)
  conv0F<<<4096, 192, 0, stream>>>(x, w0q, b0, mul0, totw0, relu0, md0, act1);
  // L1: 256x256 -> 128x128x192 ; 3072 one-wave blocks ; direct epilogue
  convS<192, 256, 256, 128, 128, 1, true><<<dim3(3072, 1), 64, 0, stream>>>(
      (const signed char*)act1, w1p, b1, mul1, totw1, relu1, md1, zbuf, act2, nullptr);
  // L2: 128x128 -> 64x64x192 ; split-K 5 -> 3840 one-wave blocks ; i32 partials
  convS<192, 128, 128, 64, 64, 5, false><<<dim3(768, 5), 64, 0, stream>>>(
      (const signed char*)act2, w2p, b2, mul2, totw2, relu2, md2, zbuf, nullptr, partl);
  reduce2<<<3072, 256, 0, stream>>>(partl, b2, mul2, totw2, relu2, md2, act3);
  // L3: 64x64 -> 32x32x320 ; split-K 5 -> 1600 one-wave blocks ; i32 partials
  convS<320, 64, 64, 32, 32, 5, false><<<dim3(320, 5), 64, 0, stream>>>(
      (const signed char*)act3, w3p, b3, mul3, totw3, nullptr, md3, zbuf, nullptr, partl);
  reduce3<<<5120, 256, 0, stream>>>(partl, b3, mul3, totw3, md3, ga, (float*)d_out);
}

// Round 12
// 377.900 us; speedup vs baseline: 1.2460x; 1.2460x over previous
//
#include <hip/hip_runtime.h>
#include <hip/hip_bf16.h>

typedef int i32x4 __attribute__((ext_vector_type(4)));
typedef unsigned int u32;
typedef unsigned long long u64;
typedef long long ll;

// async 16B global->LDS copy. LDS dest = wave-uniform base + lane*16.
__device__ __forceinline__ void load_lds16(const void* g, void* l) {
  __builtin_amdgcn_global_load_lds(
      (const __attribute__((address_space(1))) u32*)g,
      (__attribute__((address_space(3))) u32*)l, 16, 0, 0);
}

// ---------------------------------------------------------------------------
// prep_all: weight packing via LDS transpose (coalesced reads) + totw sums.
// Grid: [0,88) transpose blocks (each owns 8 oc of one mf-half);
//       blk==88: w0q custom pack + zbuf + w0 sums.
//   wNp : i8 [s=tap*3+ch][mf(MF)][q4][col16][e16]; ci = ch*64+q*16+e
//   w0q : i8 [ch2][mf12][q4][colA16][e16], CUSTOM k-order:
//         ch0: ky=q, ci=e/5, kx=e%5 (e<15); ch1: q==0 -> ky=4; all else 0.
//   zbuf : 0x80 fill (B-pad reads give value-128 uniformly)
// ---------------------------------------------------------------------------
__global__ __launch_bounds__(256) void prep_all(
    const float* __restrict__ w0, const float* __restrict__ w1,
    const float* __restrict__ w2, const float* __restrict__ w3,
    signed char* __restrict__ w0q, signed char* __restrict__ w1p,
    signed char* __restrict__ w2p, signed char* __restrict__ w3p,
    signed char* __restrict__ zbuf,
    int* __restrict__ totw0, int* __restrict__ totw1,
    int* __restrict__ totw2, int* __restrict__ totw3)
{
  __shared__ signed char ldsw[8 * 4800];   // 38400 B
  const int blk = blockIdx.x;
  const int tid = threadIdx.x;

  if (blk < 88) {
    const float* wsrc; signed char* wdst; int* tot; int MF, sub;
    if (blk < 24)      { wsrc = w1; wdst = w1p; tot = totw1; MF = 12; sub = blk; }
    else if (blk < 48) { wsrc = w2; wdst = w2p; tot = totw2; MF = 12; sub = blk - 24; }
    else               { wsrc = w3; wdst = w3p; tot = totw3; MF = 20; sub = blk - 48; }
    const int mf = sub >> 1, half = sub & 1, colbase = half * 8;
    const int ocb = mf * 16 + colbase;
    for (int o = 0; o < 8; o++) {
      const float* src = wsrc + (size_t)(ocb + o) * 4800;
      int s = 0;
      for (int j = tid; j < 4800; j += 256) {
        int v = (int)rintf(src[j]);
        ldsw[o * 4800 + j] = (signed char)v;
        s += v;
      }
      atomicAdd(&tot[ocb + o], s);
    }
    __syncthreads();
    for (int u = tid; u < 9600; u += 256) {
      int eu = u & 3, colL = (u >> 2) & 7, q = (u >> 5) & 3, t = u >> 7;
      int tap = t / 3, ch = t - 3 * tap;
      int ci0 = ch * 64 + q * 16 + eu * 4;
      const signed char* sp = ldsw + colL * 4800 + tap;
      u32 wv = 0;
      #pragma unroll
      for (int bb = 0; bb < 4; bb++)
        wv |= ((u32)(unsigned char)sp[(ci0 + bb) * 25]) << (8 * bb);
      *(u32*)(wdst + ((size_t)t * MF + mf) * 1024 +
              (q * 16 + colbase + colL) * 16 + eu * 4) = wv;
    }
  } else {
    if (tid < 128) ((u64*)zbuf)[tid] = 0x8080808080808080ULL;
    for (int i = tid; i < 24576; i += 256) {
      int e = i & 15, colA = (i >> 4) & 15, q = (i >> 8) & 3, t = i >> 10;
      int mf = t % 12, ch = t / 12;
      signed char v = 0;
      if (e < 15 && (ch == 0 || q == 0)) {
        int ky = (ch == 0) ? q : 4;
        int ci = e / 5, kx = e - ci * 5;
        v = (signed char)(int)rintf(
            w0[((mf * 16 + colA) * 3 + ci) * 25 + ky * 5 + kx]);
      }
      w0q[i] = v;
    }
    for (int oc = tid; oc < 192; oc += 256) {
      const float* p = w0 + (size_t)oc * 75;
      int s = 0;
      #pragma unroll 5
      for (int j = 0; j < 75; j++) s += (int)rintf(p[j]);
      totw0[oc] = s;
    }
  }
}

// ---------------------------------------------------------------------------
// conv0F: fused layer-0 (unchanged from R10). Block = 64-px strip, 3 waves.
// ---------------------------------------------------------------------------
__global__ __launch_bounds__(192, 3) void conv0F(
    const float* __restrict__ x, const signed char* __restrict__ wq,
    const float* __restrict__ bias, const float* __restrict__ mulv,
    const int* __restrict__ totw,
    const int* __restrict__ reluP, const int* __restrict__ mdP,
    unsigned char* __restrict__ outA)
{
  __shared__ signed char ilds[3][5][132];

  const int tid = threadIdx.x;
  const int lane = tid & 63;
  const int col = lane & 15;
  const int quad = lane >> 4;
  const int w = tid >> 6;
  const int blk = blockIdx.x;
  const int oxblk = blk & 3;
  const int oy = (blk >> 2) & 255;
  const int b = blk >> 10;
  const int oxbase = oxblk * 64;

  i32x4 afr[2][4];
  #pragma unroll
  for (int ch = 0; ch < 2; ch++)
    #pragma unroll
    for (int i = 0; i < 4; i++)
      afr[ch][i] = *(const i32x4*)(wq + ch * 12288 + (w * 4 + i) * 1024 + lane * 16);

  const float* xb = x + (size_t)b * 3 * 512 * 512;
  for (int i = tid; i < 990; i += 192) {
    int j = i % 66; int t = i / 66; int r = t % 5; int ci = t / 5;
    int iy = 2 * oy - 2 + r;
    int ix = 2 * oxbase - 2 + 2 * j;
    int v0 = -128, v1 = -128;
    if ((unsigned)iy < 512u) {
      const float* row = xb + ((size_t)ci * 512 + iy) * 512;
      if ((unsigned)ix < 512u) {
        float xv = rintf(row[ix] * 256.0f);
        v0 = (int)fminf(fmaxf(xv, 0.0f), 255.0f) - 128;
      }
      if ((unsigned)(ix + 1) < 512u) {
        float xv = rintf(row[ix + 1] * 256.0f);
        v1 = (int)fminf(fmaxf(xv, 0.0f), 255.0f) - 128;
      }
    }
    *(unsigned short*)&ilds[ci][r][2 * j] =
        (unsigned short)((v0 & 0xFF) | ((v1 & 0xFF) << 8));
  }
  __syncthreads();

  i32x4 acc[4][4];
  #pragma unroll
  for (int fm = 0; fm < 4; fm++)
    #pragma unroll
    for (int fn = 0; fn < 4; fn++) acc[fm][fn] = (i32x4){0, 0, 0, 0};

  #pragma unroll
  for (int ch = 0; ch < 2; ch++) {
    const int row = (ch == 0) ? quad : 4;
    i32x4 bfr[4];
    #pragma unroll
    for (int fn = 0; fn < 4; fn++) {
      const int xb2 = 2 * (fn * 16 + col);
      const int o8 = (xb2 & 3) * 8;
      const int ab = xb2 & ~3;
      u64 w0_, w1_, w2_;
      {
        const u32* p0 = (const u32*)&ilds[0][row][ab];
        const u32* p1 = (const u32*)&ilds[1][row][ab];
        const u32* p2 = (const u32*)&ilds[2][row][ab];
        w0_ = (u64)p0[0] | ((u64)p0[1] << 32);
        w1_ = (u64)p1[0] | ((u64)p1[1] << 32);
        w2_ = (u64)p2[0] | ((u64)p2[1] << 32);
      }
      u32 a0 = (u32)(w0_ >> o8);
      u32 a1 = ((u32)(w0_ >> (o8 + 32)) & 0xFFu) | (((u32)(w1_ >> o8)) << 8);
      u32 a2 = ((u32)(w1_ >> (o8 + 24)) & 0xFFFFu) | (((u32)(w2_ >> o8)) << 16);
      u32 a3 = (u32)(w2_ >> (o8 + 16));
      bfr[fn] = (i32x4){(int)a0, (int)a1, (int)a2, (int)a3};
    }
    #pragma unroll
    for (int fm = 0; fm < 4; fm++)
      #pragma unroll
      for (int fn = 0; fn < 4; fn++)
        acc[fm][fn] = __builtin_amdgcn_mfma_i32_16x16x64_i8(
            afr[ch][fm], bfr[fn], acc[fm][fn], 0, 0, 0);
  }

  const size_t pix0 = ((size_t)(b * 256 + oy)) * 256 + oxbase;
  const int rl = reluP[0];
  const int sh = mdP[0];
  const ll clpv_ll = llrint(255.0 / (double)rl * 16777216.0);
  const int clpv = clpv_ll > 0x7FFFFFFFLL ? 0x7FFFFFFF : (int)clpv_ll;
  const int sclv = (int)((rl + 4) >> 3);
  const int rnd = 1 << (sh - 1);
  #pragma unroll
  for (int fm = 0; fm < 4; fm++) {
    const int oc0 = w * 64 + fm * 16 + quad * 4;
    int bim[4], mu32[4];
    #pragma unroll
    for (int r = 0; r < 4; r++) {
      int bi = (int)llrintf(bias[oc0 + r] * 256.0f) + 128 * totw[oc0 + r];
      mu32[r] = (int)llrintf(mulv[oc0 + r]);
      bim[r] = bi * mu32[r];
    }
    #pragma unroll
    for (int fn = 0; fn < 4; fn++) {
      const size_t pix = pix0 + fn * 16 + col;
      u32 wd = 0;
      #pragma unroll
      for (int r = 0; r < 4; r++) {
        int vi = acc[fm][fn][r] * mu32[r] + bim[r];
        int y = (vi + rnd) >> sh;
        y = y < 0 ? 0 : (y > clpv ? clpv : y);
        y = (y * sclv + (1 << 20)) >> 21;
        wd |= (((u32)y ^ 0x80u) & 0xFFu) << (8 * r);
      }
      *(u32*)(outA + pix * 192 + oc0) = wd;
    }
  }
}

// ---------------------------------------------------------------------------
// Layers 1-3: implicit GEMM, single barrier per K-step (R10-proven), x2
// unrolled with two A-register banks + incremental kx/ky/ch staging state.
// FN = oy rows per block (pixel tile = 16 x FN). FN=2 for L1 doubles the
// grid -> 8 blocks/CU (A dup absorbed by L1/L2; B traffic/output unchanged).
// OCC = min waves/EU for __launch_bounds__.
// ---------------------------------------------------------------------------
template <int COUT, int HIN, int WIN, int HOUT, int WOUT, int MW, int FN,
          int KSPLIT, bool DIRECT, int OCC>
__global__ __launch_bounds__(MW * 64, OCC) void convS(
    const signed char* __restrict__ act, const signed char* __restrict__ wp,
    const float* __restrict__ bias, const float* __restrict__ mulv,
    const int* __restrict__ totw,
    const int* __restrict__ reluP, const int* __restrict__ mdP,
    const signed char* __restrict__ zbuf,
    unsigned char* __restrict__ outA, int* __restrict__ outP)
{
  constexpr int CIN = 192;
  constexpr int PASSES = FN;
  constexpr int MAXP = (PASSES + MW - 1) / MW;
  constexpr int SAe = MW * 4096;
  constexpr int TX = WOUT / 16;
  constexpr int TYB = HOUT / FN;
  constexpr int TPP = 25 / KSPLIT;
  constexpr int NSTEP = TPP * 3;
  constexpr int PSZ = 4 * HOUT * WOUT * COUT;
  static_assert(MW * 64 == COUT, "M covers COUT");

  __shared__ __align__(16) char smem[2 * FN * 1024];

  const int tid = threadIdx.x;
  const int lane = tid & 63;
  const int col = lane & 15;
  const int quad = lane >> 4;
  const int w = tid >> 6;
  const int part = blockIdx.y;

  int bx = blockIdx.x;
  const int tx = bx % TX; bx /= TX;
  const int ty = bx % TYB;
  const int b = bx / TYB;
  const int ox0 = tx * 16;
  const int oy0 = ty * FN;

  const signed char* bptr[MAXP];
  int bmx[MAXP], bmy[MAXP];
  #pragma unroll
  for (int k = 0; k < MAXP; k++) {
    int p = w + k * MW;
    if (p >= PASSES) break;
    int oxv = ox0 + col;
    int oyv = oy0 + p;
    bptr[k] = act + ((size_t)b * HIN * WIN + (size_t)(2 * oyv) * WIN + 2 * oxv) * CIN
              + quad * 16;
    int mx = 0, my = 0;
    #pragma unroll
    for (int kk = 0; kk < 5; kk++) {
      if ((unsigned)(2 * oxv + kk - 2) < (unsigned)WIN) mx |= 1 << kk;
      if ((unsigned)(2 * oyv + kk - 2) < (unsigned)HIN) my |= 1 << kk;
    }
    bmx[k] = mx; bmy[k] = my;
  }

  // staging state: (kxS, kyS, chS) of the NEXT step to stage
  int kxS, kyS, chS;

  auto stage = [&](int sel) {
    const int offB = ((kyS - 2) * WIN + (kxS - 2)) * CIN + chS * 64;
    #pragma unroll
    for (int k = 0; k < MAXP; k++) {
      int p = w + k * MW;
      if (p >= PASSES) break;
      bool v = ((bmx[k] >> kxS) & 1) && ((bmy[k] >> kyS) & 1);
      const signed char* g = v ? (bptr[k] + offB) : (zbuf + quad * 16);
      load_lds16(g, smem + sel * (FN * 1024) + p * 1024);
    }
  };
  auto adv = [&]() {
    chS++;
    if (chS == 3) { chS = 0; kxS++; if (kxS == 5) { kxS = 0; kyS++; } }
  };

  i32x4 acc[4][FN];
  #pragma unroll
  for (int fm = 0; fm < 4; fm++)
    #pragma unroll
    for (int fn = 0; fn < FN; fn++) acc[fm][fn] = (i32x4){0, 0, 0, 0};

  // preload: stage step0 -> buf0 ; A(0) -> aA
  const int tap0 = part * TPP;
  kyS = tap0 / 5; kxS = tap0 - 5 * kyS; chS = 0;
  stage(0);
  adv();
  const signed char* aptr = wp + (size_t)(tap0 * 3) * SAe + w * 4096 + lane * 16;
  i32x4 aA[4], aB[4];
  #pragma unroll
  for (int i = 0; i < 4; i++) aA[i] = *(const i32x4*)(aptr + i * 1024);

  auto comp = [&](int base, i32x4 (&a)[4]) {
    const char* pB = smem + base + lane * 16;
    i32x4 bfr[FN];
    #pragma unroll
    for (int i = 0; i < FN; i++)
      bfr[i] = *(const i32x4*)(pB + i * 1024);
    #pragma unroll
    for (int fm = 0; fm < 4; fm++)
      #pragma unroll
      for (int fn = 0; fn < FN; fn++)
        acc[fm][fn] = __builtin_amdgcn_mfma_i32_16x16x64_i8(
            a[fm], bfr[fn], acc[fm][fn], 0, 0, 0);
  };

  int sl = 0;
  #pragma unroll 1
  for (; sl + 1 < NSTEP; sl += 2) {
    __syncthreads();                 // buf0 (step sl) staged & drained
    stage(1); adv();                 // stage step sl+1 -> buf1
    aptr += SAe;                     // A(sl+1) -> aB
    #pragma unroll
    for (int i = 0; i < 4; i++) aB[i] = *(const i32x4*)(aptr + i * 1024);
    comp(0, aA);

    __syncthreads();                 // buf1 (step sl+1) staged & drained
    if (sl + 2 < NSTEP) {
      stage(0); adv();               // stage step sl+2 -> buf0
      aptr += SAe;                   // A(sl+2) -> aA
      #pragma unroll
      for (int i = 0; i < 4; i++) aA[i] = *(const i32x4*)(aptr + i * 1024);
    }
    comp(FN * 1024, aB);
  }
  if (sl < NSTEP) {                  // tail (NSTEP odd)
    __syncthreads();
    comp(0, aA);
  }

  // ---- epilogue ----
  if constexpr (DIRECT) {
    const int rl = reluP[0];
    const int sh = mdP[0] - 8;
    const ll clpv = llrint(255.0 / (double)rl * 16777216.0);
    const ll sclv = (ll)((rl + 4) >> 3);
    #pragma unroll
    for (int fm = 0; fm < 4; fm++) {
      const int oc0 = w * 64 + fm * 16 + quad * 4;
      ll bi[4], mu[4];
      #pragma unroll
      for (int r = 0; r < 4; r++) {
        bi[r] = llrintf(bias[oc0 + r]) + 128LL * totw[oc0 + r];
        mu[r] = llrintf(mulv[oc0 + r]);
      }
      #pragma unroll
      for (int fn = 0; fn < FN; fn++) {
        const int oyv = oy0 + fn;
        const int oxv = ox0 + col;
        u32 wd = 0;
        #pragma unroll
        for (int r = 0; r < 4; r++) {
          ll vi = ((ll)acc[fm][fn][r] + bi[r]) * mu[r];
          ll y = (vi + (1LL << (sh - 1))) >> sh;
          y = y < 0 ? 0LL : (y > clpv ? clpv : y);
          y = (y * sclv + (1LL << 20)) >> 21;
          wd |= (((u32)y ^ 0x80u) & 0xFFu) << (8 * r);
        }
        *(u32*)(outA + ((size_t)((b * HOUT + oyv) * WOUT + oxv)) * COUT + oc0) = wd;
      }
    }
  } else {
    int* pout = outP + (size_t)part * PSZ;
    #pragma unroll
    for (int fm = 0; fm < 4; fm++) {
      const int oc0 = w * 64 + fm * 16 + quad * 4;
      #pragma unroll
      for (int fn = 0; fn < FN; fn++) {
        const int oyv = oy0 + fn;
        const int oxv = ox0 + col;
        *(i32x4*)(pout + ((size_t)((b * HOUT + oyv) * WOUT + oxv)) * COUT + oc0) =
            acc[fm][fn];
      }
    }
  }
}

// ---------------------------------------------------------------------------
// reduce2: sum 5 L2 partials + integer epilogue -> act3 (i8, channels-last).
// ---------------------------------------------------------------------------
__global__ __launch_bounds__(256) void reduce2(
    const int* __restrict__ partP, const float* __restrict__ bias,
    const float* __restrict__ mulv, const int* __restrict__ totw,
    const int* __restrict__ reluP, const int* __restrict__ mdP,
    unsigned char* __restrict__ outA)
{
  const int gid = blockIdx.x * 256 + threadIdx.x;   // 786432
  const int PSZ4 = 4 * 64 * 64 * 192 / 4;
  const int4* pp = (const int4*)partP;
  int4 sv = pp[gid];
  #pragma unroll
  for (int p = 1; p < 5; p++) {
    int4 v = pp[(size_t)p * PSZ4 + gid];
    sv.x += v.x; sv.y += v.y; sv.z += v.z; sv.w += v.w;
  }
  int sa[4] = {sv.x, sv.y, sv.z, sv.w};
  const int oc0 = (gid * 4) % 192;
  const int rl = reluP[0];
  const int sh = mdP[0] - 8;
  const ll clpv = llrint(255.0 / (double)rl * 16777216.0);
  const ll sclv = (ll)((rl + 4) >> 3);
  u32 wd = 0;
  #pragma unroll
  for (int r = 0; r < 4; r++) {
    ll bi = llrintf(bias[oc0 + r]) + 128LL * totw[oc0 + r];
    ll mu = llrintf(mulv[oc0 + r]);
    ll vi = ((ll)sa[r] + bi) * mu;
    ll y = (vi + (1LL << (sh - 1))) >> sh;
    y = y < 0 ? 0LL : (y > clpv ? clpv : y);
    y = (y * sclv + (1LL << 20)) >> 21;
    wd |= (((u32)y ^ 0x80u) & 0xFFu) << (8 * r);
  }
  ((u32*)outA)[gid] = wd;
}

// ---------------------------------------------------------------------------
// reduce3: sum 5 L3 partials + final shift -> d_out f32 NCHW (coalesced write).
// ---------------------------------------------------------------------------
__global__ __launch_bounds__(256) void reduce3(
    const int* __restrict__ partP, const float* __restrict__ b3,
    const float* __restrict__ mul3, const int* __restrict__ totw3,
    const int* __restrict__ mdP, const int* __restrict__ gaP,
    float* __restrict__ outF)
{
  const int gid = blockIdx.x * 256 + threadIdx.x;   // 1310720
  int t = gid;
  const int ox = t & 31; t >>= 5;
  const int oy = t & 31; t >>= 5;
  const int oc = t % 320;
  const int b  = t / 320;
  const int PSZ = 4 * 32 * 32 * 320;
  const size_t src = ((size_t)((b * 32 + oy) * 32 + ox)) * 320 + oc;
  ll s = 0;
  #pragma unroll
  for (int p = 0; p < 5; p++) s += partP[(size_t)p * PSZ + src];
  const int sh = mdP[0] - gaP[0];
  const ll bi = llrintf(b3[oc]) + 128LL * totw3[oc];
  const ll mu = llrintf(mul3[oc]);
  const ll y = ((s + bi) * mu + (1LL << (sh - 1))) >> sh;
  outF[gid] = (float)y;
}

// ---------------------------------------------------------------------------
extern "C" void kernel_launch(void* const* d_in, const int* in_sizes, int n_in,
                              void* d_out, int out_size, void* d_ws, size_t ws_size,
                              hipStream_t stream)
{
  const float* x    = (const float*)d_in[0];
  const float* w0   = (const float*)d_in[1];
  const float* b0   = (const float*)d_in[2];
  const float* w1   = (const float*)d_in[3];
  const float* b1   = (const float*)d_in[4];
  const float* w2   = (const float*)d_in[5];
  const float* b2   = (const float*)d_in[6];
  const float* w3   = (const float*)d_in[7];
  const float* b3   = (const float*)d_in[8];
  const float* mul0 = (const float*)d_in[9];
  const float* mul1 = (const float*)d_in[10];
  const float* mul2 = (const float*)d_in[11];
  const float* mul3 = (const float*)d_in[12];
  const int* relu0  = (const int*)d_in[13];
  const int* relu1  = (const int*)d_in[14];
  const int* relu2  = (const int*)d_in[15];
  const int* md0    = (const int*)d_in[16];
  const int* md1    = (const int*)d_in[17];
  const int* md2    = (const int*)d_in[18];
  const int* md3    = (const int*)d_in[19];
  const int* ga     = (const int*)d_in[20];

  char* ws = (char*)d_ws;
  size_t off = 0;
  signed char* zbuf = (signed char*)(ws + off); off += 1024;
  signed char* w0q  = (signed char*)(ws + off); off += 24576;
  signed char* w1p  = (signed char*)(ws + off); off += 921600;
  signed char* w2p  = (signed char*)(ws + off); off += 921600;
  signed char* w3p  = (signed char*)(ws + off); off += 1536000;
  int*         totw1= (int*)        (ws + off); off += 192 * 4;
  int*         totw2= (int*)        (ws + off); off += 192 * 4;
  int*         totw3= (int*)        (ws + off); off += 320 * 4;
  int*         totw0= (int*)        (ws + off); off += 192 * 4;
  unsigned char* act1 = (unsigned char*)(ws + off); off += (size_t)4 * 256 * 256 * 192;
  unsigned char* act2 = (unsigned char*)(ws + off); off += (size_t)4 * 128 * 128 * 192;
  unsigned char* act3 = (unsigned char*)(ws + off); off += (size_t)4 * 64 * 64 * 192;
  int*         partl  = (int*)(ws + off); off += (size_t)5 * 4 * 64 * 64 * 192 * 4; // 62.9MB
  (void)ws_size; (void)in_sizes; (void)n_in; (void)out_size;

  hipMemsetAsync(totw1, 0, (192 + 192 + 320 + 192) * 4, stream);
  // weight packing (LDS transpose) + weight sums
  prep_all<<<89, 256, 0, stream>>>(w0, w1, w2, w3, w0q, w1p, w2p, w3p,
                                   zbuf, totw0, totw1, totw2, totw3);
  // L0 fused: quantize + in-register im2col + GEMM (M=192, N=262144, K=128)
  conv0F<<<4096, 192, 0, stream>>>(x, w0q, b0, mul0, totw0, relu0, md0, act1);
  // L1: 256x256 -> 128x128x192 ; FN=2 -> 2048 blocks x 3 waves (8 blocks/CU)
  convS<192, 256, 256, 128, 128, 3, 2, 1, true, 6><<<dim3(2048, 1), 192, 0, stream>>>(
      (const signed char*)act1, w1p, b1, mul1, totw1, relu1, md1, zbuf, act2, nullptr);
  // L2: 128x128 -> 64x64x192 ; FN=4, split-K 5 -> 1280 blocks ; i32 partials
  convS<192, 128, 128, 64, 64, 3, 4, 5, false, 3><<<dim3(256, 5), 192, 0, stream>>>(
      (const signed char*)act2, w2p, b2, mul2, totw2, relu2, md2, zbuf, nullptr, partl);
  reduce2<<<3072, 256, 0, stream>>>(partl, b2, mul2, totw2, relu2, md2, act3);
  // L3: 64x64 -> 32x32x320 ; FN=4, split-K 5 -> 320 blocks ; i32 partials
  convS<320, 64, 64, 32, 32, 5, 4, 5, false, 3><<<dim3(64, 5), 320, 0, stream>>>(
      (const signed char*)act3, w3p, b3, mul3, totw3, nullptr, md3, zbuf, nullptr, partl);
  reduce3<<<5120, 256, 0, stream>>>(partl, b3, mul3, totw3, md3, ga, (float*)d_out);
}